// Round 1
// baseline (1184.670 us; speedup 1.0000x reference)
//
#include <hip/hip_runtime.h>
#include <math.h>

#define B_ 512
#define S_ 2048
#define E_DIM 64
#define P_DIM 32
#define H_DIM 64
#define NEGV (-4294967295.0f)   // -2^32 + 1

__device__ __forceinline__ float wave_reduce_sum(float v) {
#pragma unroll
  for (int m = 32; m >= 1; m >>= 1) v += __shfl_xor(v, m, 64);
  return v;
}

__device__ __forceinline__ float wave_reduce_max(float v) {
#pragma unroll
  for (int m = 32; m >= 1; m >>= 1) v = fmaxf(v, __shfl_xor(v, m, 64));
  return v;
}

__device__ __forceinline__ float tanh_fast(float x) {
  // tanh(x) = 1 - 2/(exp(2x)+1); exact at +/-inf limits, ~1e-6 rel err
  float e = __expf(2.0f * x);
  return 1.0f - 2.0f * __builtin_amdgcn_rcpf(e + 1.0f);
}

__global__ __launch_bounds__(256, 2) void item2item_kernel(
    const float* __restrict__ seq_items, const float* __restrict__ seq_pos,
    const float* __restrict__ target_item, const float* __restrict__ Wp,
    const float* __restrict__ We, const float* __restrict__ Wc,
    const float* __restrict__ bias, const float* __restrict__ z,
    const int* __restrict__ seq_len, float* __restrict__ out) {
  __shared__ float a_tile[64];
  __shared__ float w_tile[64];
  __shared__ float u_part[256];
  __shared__ float m_sh, l_sh, r_sh, scale_sh;

  const int b = blockIdx.x;
  const int tid = threadIdx.x;
  const int h = tid & 63;   // lane within wave = h (and e for u-accum)
  const int wv = tid >> 6;  // wave id 0..3
  const int L = seq_len[b];

  float* __restrict__ out_u = out;              // [B, 64]
  float* __restrict__ out_r = out + B_ * E_DIM; // [B]

  const float* __restrict__ itemsB = seq_items + (size_t)b * S_ * E_DIM;
  const float* __restrict__ posB = seq_pos + (size_t)b * S_ * P_DIM;

  if (L == 0) {
    // softmax over all-NEG logits is uniform -> u = mean(items), r = 0
    float acc = 0.0f;
    for (int s = wv; s < S_; s += 4) acc += itemsB[(size_t)s * E_DIM + h];
    u_part[tid] = acc;
    __syncthreads();
    if (tid < 64) {
      float v = u_part[tid] + u_part[tid + 64] + u_part[tid + 128] + u_part[tid + 192];
      out_u[b * E_DIM + tid] = v * (1.0f / (float)S_);
    }
    if (tid == 0) out_r[b] = 0.0f;
    return;
  }

  // ---- preload per-h weight columns into registers ----
  float wI[E_DIM], wP[P_DIM];
#pragma unroll
  for (int e = 0; e < E_DIM; ++e) wI[e] = We[e * H_DIM + h];
#pragma unroll
  for (int p = 0; p < P_DIM; ++p) wP[p] = Wp[p * H_DIM + h];
  const float z_reg = z[h];

  // c[h] + bias[h]  (redundant across waves, trivial cost)
  float c_reg = bias[h];
  {
    const float* __restrict__ t = target_item + b * 64;
#pragma unroll
    for (int e = 0; e < 64; ++e) c_reg = fmaf(t[e], Wc[e * H_DIM + h], c_reg);
  }

  if (tid == 0) {
    m_sh = -INFINITY;
    l_sh = 0.0f;
    r_sh = 0.0f;
  }
  __syncthreads();

  float u_acc = 0.0f;
  const int nT = (L + 63) >> 6;

  for (int t = 0; t < nT; ++t) {
    const int s0 = t << 6;

    // ---- phase 1: a[s] for this tile; wave wv does s_loc = wv + 4k ----
#pragma unroll 1
    for (int k = 0; k < 16; ++k) {
      const int s_loc = wv + (k << 2);
      const int s_idx = __builtin_amdgcn_readfirstlane(s0 + s_loc);
      const float4* __restrict__ rowI = (const float4*)(itemsB + (size_t)s_idx * E_DIM);
      const float4* __restrict__ rowP = (const float4*)(posB + (size_t)s_idx * P_DIM);
      float acc = c_reg;
#pragma unroll
      for (int e4 = 0; e4 < E_DIM / 4; ++e4) {
        float4 x = rowI[e4];
        acc = fmaf(x.x, wI[4 * e4 + 0], acc);
        acc = fmaf(x.y, wI[4 * e4 + 1], acc);
        acc = fmaf(x.z, wI[4 * e4 + 2], acc);
        acc = fmaf(x.w, wI[4 * e4 + 3], acc);
      }
#pragma unroll
      for (int p4 = 0; p4 < P_DIM / 4; ++p4) {
        float4 x = rowP[p4];
        acc = fmaf(x.x, wP[4 * p4 + 0], acc);
        acc = fmaf(x.y, wP[4 * p4 + 1], acc);
        acc = fmaf(x.z, wP[4 * p4 + 2], acc);
        acc = fmaf(x.w, wP[4 * p4 + 3], acc);
      }
      float v = tanh_fast(acc) * z_reg;
      v = wave_reduce_sum(v);
      if (h == 0) a_tile[s_loc] = v;
    }
    __syncthreads();

    // ---- phase 2: online-softmax stats (wave 0 only) ----
    if (wv == 0) {
      const int sg = s0 + tid;
      const float a = a_tile[tid];
      const bool valid = sg < L;
      const float aval = valid ? a : NEGV;
      const float mx = wave_reduce_max(aval);
      const float m_old = m_sh;  // all lanes read before lane0 writes
      const float m_new = fmaxf(m_old, mx);
      const float sc = __expf(m_old - m_new);   // first tile: exp(-inf)=0
      const float w = __expf(aval - m_new);     // masked: exp(~-4e9)=0
      w_tile[tid] = w;
      const float sw = wave_reduce_sum(w);
      const float ra = wave_reduce_sum(valid ? a : 0.0f);
      if (tid == 0) {
        l_sh = l_sh * sc + sw;
        r_sh += ra;
        m_sh = m_new;
        scale_sh = sc;
      }
    }
    __syncthreads();

    // ---- phase 3: u accumulation (coalesced, L1-hot re-read) ----
    const float sc = scale_sh;
    u_acc *= sc;
#pragma unroll
    for (int k = 0; k < 16; ++k) {
      const int s_loc = wv + (k << 2);
      const float wk = w_tile[s_loc];  // wave-uniform broadcast
      u_acc = fmaf(wk, itemsB[(size_t)(s0 + s_loc) * E_DIM + h], u_acc);
    }
    // w_tile is rewritten only after the next phase-1 __syncthreads(),
    // so the 2-barrier-per-tile pattern is race-free.
  }

  __syncthreads();
  u_part[tid] = u_acc;
  __syncthreads();
  if (tid < 64) {
    float v = u_part[tid] + u_part[tid + 64] + u_part[tid + 128] + u_part[tid + 192];
    out_u[b * E_DIM + tid] = v / l_sh;
  }
  if (tid == 0) out_r[b] = r_sh;
}

extern "C" void kernel_launch(void* const* d_in, const int* in_sizes, int n_in,
                              void* d_out, int out_size, void* d_ws, size_t ws_size,
                              hipStream_t stream) {
  const float* seq_items = (const float*)d_in[0];
  const float* seq_pos = (const float*)d_in[1];
  const float* target_item = (const float*)d_in[2];
  const float* Wp = (const float*)d_in[3];
  const float* We = (const float*)d_in[4];
  const float* Wc = (const float*)d_in[5];
  const float* bias = (const float*)d_in[6];
  const float* z = (const float*)d_in[7];
  const int* seq_len = (const int*)d_in[8];
  float* out = (float*)d_out;

  item2item_kernel<<<B_, 256, 0, stream>>>(seq_items, seq_pos, target_item, Wp,
                                           We, Wc, bias, z, seq_len, out);
}

// Round 2
// 678.405 us; speedup vs baseline: 1.7463x; 1.7463x over previous
//
#include <hip/hip_runtime.h>
#include <math.h>

#define B_ 512
#define S_ 2048
#define E_DIM 64
#define P_DIM 32
#define H_DIM 64
#define NEGV (-4294967295.0f)   // -2^32 + 1

__device__ __forceinline__ float wave_reduce_sum(float v) {
#pragma unroll
  for (int m = 32; m >= 1; m >>= 1) v += __shfl_xor(v, m, 64);
  return v;
}

__device__ __forceinline__ float wave_reduce_max(float v) {
#pragma unroll
  for (int m = 32; m >= 1; m >>= 1) v = fmaxf(v, __shfl_xor(v, m, 64));
  return v;
}

__device__ __forceinline__ float tanh_fast(float x) {
  float e = __expf(2.0f * x);
  return 1.0f - 2.0f * __builtin_amdgcn_rcpf(e + 1.0f);
}

// ---------------------------------------------------------------------------
// K1: a[b,s] = sum_h tanh(c[b,h] + items[b,s,:]@We[:,h] + pos[b,s,:]@Wp[:,h]
//                          + bias[h]) * z[h]
// Grid: B_ * (S_/64) blocks of 256. Tile of 64 positions staged in LDS.
// Lane = h; per-lane weight columns in VGPRs; X rows broadcast from LDS.
// ---------------------------------------------------------------------------
__global__ __launch_bounds__(256) void scores_kernel(
    const float* __restrict__ seq_items, const float* __restrict__ seq_pos,
    const float* __restrict__ target_item, const float* __restrict__ Wp,
    const float* __restrict__ We, const float* __restrict__ Wc,
    const float* __restrict__ bias, const float* __restrict__ z,
    const int* __restrict__ seq_len, float* __restrict__ a_out) {
  const int blk = blockIdx.x;
  const int b = blk >> 5;    // 32 tiles per batch row
  const int t = blk & 31;
  const int s0 = t << 6;
  const int L = seq_len[b];
  if (s0 >= L) return;  // includes L==0 (handled in K2/K3)

  __shared__ float ldsI[64 * E_DIM];  // 16 KB, tile rows contiguous
  __shared__ float ldsP[64 * P_DIM];  // 8 KB

  const int tid = threadIdx.x;
  const int h = tid & 63;
  const int wv = tid >> 6;

  // ---- stage tile (both tiles are contiguous in global memory) ----
  const float4* __restrict__ gI =
      (const float4*)(seq_items + ((size_t)b * S_ + s0) * E_DIM);
  float4* sI = (float4*)ldsI;
#pragma unroll
  for (int i = 0; i < 4; ++i) sI[tid + 256 * i] = gI[tid + 256 * i];
  const float4* __restrict__ gP =
      (const float4*)(seq_pos + ((size_t)b * S_ + s0) * P_DIM);
  float4* sP = (float4*)ldsP;
#pragma unroll
  for (int i = 0; i < 2; ++i) sP[tid + 256 * i] = gP[tid + 256 * i];

  // ---- per-lane weight columns (coalesced across lanes) ----
  float wI[E_DIM], wP[P_DIM];
#pragma unroll
  for (int e = 0; e < E_DIM; ++e) wI[e] = We[e * H_DIM + h];
#pragma unroll
  for (int p = 0; p < P_DIM; ++p) wP[p] = Wp[p * H_DIM + h];
  const float z_reg = z[h];
  float c_reg = bias[h];
  {
    const float* __restrict__ tg = target_item + b * 64;
#pragma unroll
    for (int e = 0; e < 64; ++e) c_reg = fmaf(tg[e], Wc[e * H_DIM + h], c_reg);
  }
  __syncthreads();

  float* __restrict__ aB = a_out + (size_t)b * S_ + s0;

  // 16 positions per wave; unroll 2 for ILP, split accumulators per position
#pragma unroll 2
  for (int k = 0; k < 16; ++k) {
    const int s_loc = wv * 16 + k;
    const float4* rI = (const float4*)(ldsI + s_loc * E_DIM);
    const float4* rP = (const float4*)(ldsP + s_loc * P_DIM);
    float acc0 = c_reg, acc1 = 0.0f;
#pragma unroll
    for (int e4 = 0; e4 < 8; ++e4) {
      float4 x = rI[e4];
      acc0 = fmaf(x.x, wI[4 * e4 + 0], acc0);
      acc0 = fmaf(x.y, wI[4 * e4 + 1], acc0);
      acc0 = fmaf(x.z, wI[4 * e4 + 2], acc0);
      acc0 = fmaf(x.w, wI[4 * e4 + 3], acc0);
    }
#pragma unroll
    for (int e4 = 8; e4 < 16; ++e4) {
      float4 x = rI[e4];
      acc1 = fmaf(x.x, wI[4 * e4 + 0], acc1);
      acc1 = fmaf(x.y, wI[4 * e4 + 1], acc1);
      acc1 = fmaf(x.z, wI[4 * e4 + 2], acc1);
      acc1 = fmaf(x.w, wI[4 * e4 + 3], acc1);
    }
#pragma unroll
    for (int p4 = 0; p4 < 4; ++p4) {
      float4 x = rP[p4];
      acc0 = fmaf(x.x, wP[4 * p4 + 0], acc0);
      acc0 = fmaf(x.y, wP[4 * p4 + 1], acc0);
      acc0 = fmaf(x.z, wP[4 * p4 + 2], acc0);
      acc0 = fmaf(x.w, wP[4 * p4 + 3], acc0);
    }
#pragma unroll
    for (int p4 = 4; p4 < 8; ++p4) {
      float4 x = rP[p4];
      acc1 = fmaf(x.x, wP[4 * p4 + 0], acc1);
      acc1 = fmaf(x.y, wP[4 * p4 + 1], acc1);
      acc1 = fmaf(x.z, wP[4 * p4 + 2], acc1);
      acc1 = fmaf(x.w, wP[4 * p4 + 3], acc1);
    }
    float v = tanh_fast(acc0 + acc1) * z_reg;
    v = wave_reduce_sum(v);
    if (h == 0) aB[s_loc] = v;
  }
}

// ---------------------------------------------------------------------------
// K2: per-b softmax stats over a[b,0:L]; writes w (in-place over a), r,
//     zeroes out_u. L==0 -> uniform w = 1/S, r = 0.
// Grid: B_ blocks of 256.
// ---------------------------------------------------------------------------
__global__ __launch_bounds__(256) void softmax_kernel(
    float* __restrict__ a_buf, const int* __restrict__ seq_len,
    float* __restrict__ out) {
  __shared__ float red[4];
  const int b = blockIdx.x;
  const int tid = threadIdx.x;
  const int wv = tid >> 6;
  const int L = seq_len[b];
  float* __restrict__ out_u = out;
  float* __restrict__ out_r = out + B_ * E_DIM;

  if (tid < 64) out_u[b * E_DIM + tid] = 0.0f;  // K3 accumulates atomically

  float* __restrict__ a = a_buf + (size_t)b * S_;

  if (L == 0) {
    const float inv = 1.0f / (float)S_;
    for (int s = tid; s < S_; s += 256) a[s] = inv;
    if (tid == 0) out_r[b] = 0.0f;
    return;
  }

  float av[8];
  float mx = -INFINITY, sa = 0.0f;
#pragma unroll
  for (int i = 0; i < 8; ++i) {
    const int s = tid + 256 * i;
    if (s < L) {
      const float x = a[s];
      av[i] = x;
      mx = fmaxf(mx, x);
      sa += x;
    } else {
      av[i] = 0.0f;
    }
  }
  // block max
  mx = wave_reduce_max(mx);
  if ((tid & 63) == 0) red[wv] = mx;
  __syncthreads();
  const float m = fmaxf(fmaxf(red[0], red[1]), fmaxf(red[2], red[3]));
  __syncthreads();

  float se = 0.0f;
  float ev[8];
#pragma unroll
  for (int i = 0; i < 8; ++i) {
    const int s = tid + 256 * i;
    if (s < L) {
      const float e = __expf(av[i] - m);
      ev[i] = e;
      se += e;
    } else {
      ev[i] = 0.0f;
    }
  }
  se = wave_reduce_sum(se);
  if ((tid & 63) == 0) red[wv] = se;
  __syncthreads();
  const float l = red[0] + red[1] + red[2] + red[3];
  __syncthreads();
  sa = wave_reduce_sum(sa);
  if ((tid & 63) == 0) red[wv] = sa;
  __syncthreads();
  const float r = red[0] + red[1] + red[2] + red[3];

  const float invl = 1.0f / l;
#pragma unroll
  for (int i = 0; i < 8; ++i) {
    const int s = tid + 256 * i;
    a[s] = (s < L) ? ev[i] * invl : 0.0f;
  }
  if (tid == 0) out_r[b] = r;
}

// ---------------------------------------------------------------------------
// K3: u[b,:] += sum_s w[b,s] * items[b,s,:]  over a 256-position chunk.
// Grid: B_ * (S_/256) blocks of 256. lane%16 = float4 column, lane/16 = row.
// ---------------------------------------------------------------------------
__global__ __launch_bounds__(256) void wsum_kernel(
    const float* __restrict__ seq_items, const float* __restrict__ w_buf,
    const int* __restrict__ seq_len, float* __restrict__ out) {
  const int blk = blockIdx.x;
  const int b = blk >> 3;  // 8 chunks per b
  const int c = blk & 7;
  const int s0 = c << 8;
  const int L = seq_len[b];
  const int Leff = (L == 0) ? S_ : L;
  if (s0 >= Leff) return;
  const int send = min(s0 + 256, Leff);

  const int tid = threadIdx.x;
  const int e4 = tid & 15;
  const int row = tid >> 4;

  const float4* __restrict__ items4 =
      (const float4*)(seq_items + (size_t)b * S_ * E_DIM);
  const float* __restrict__ w = w_buf + (size_t)b * S_;

  float4 acc = make_float4(0.f, 0.f, 0.f, 0.f);
#pragma unroll 4
  for (int s = s0 + row; s < send; s += 16) {
    const float ww = w[s];
    const float4 x = items4[s * 16 + e4];
    acc.x = fmaf(ww, x.x, acc.x);
    acc.y = fmaf(ww, x.y, acc.y);
    acc.z = fmaf(ww, x.z, acc.z);
    acc.w = fmaf(ww, x.w, acc.w);
  }

  __shared__ float4 red[256];
  red[tid] = acc;
  __syncthreads();
  if (tid < 16) {
    float4 s = red[tid];
#pragma unroll
    for (int i = 1; i < 16; ++i) {
      const float4 t2 = red[i * 16 + tid];
      s.x += t2.x; s.y += t2.y; s.z += t2.z; s.w += t2.w;
    }
    float* dst = out + b * E_DIM + tid * 4;
    atomicAdd(dst + 0, s.x);
    atomicAdd(dst + 1, s.y);
    atomicAdd(dst + 2, s.z);
    atomicAdd(dst + 3, s.w);
  }
}

extern "C" void kernel_launch(void* const* d_in, const int* in_sizes, int n_in,
                              void* d_out, int out_size, void* d_ws, size_t ws_size,
                              hipStream_t stream) {
  const float* seq_items = (const float*)d_in[0];
  const float* seq_pos = (const float*)d_in[1];
  const float* target_item = (const float*)d_in[2];
  const float* Wp = (const float*)d_in[3];
  const float* We = (const float*)d_in[4];
  const float* Wc = (const float*)d_in[5];
  const float* bias = (const float*)d_in[6];
  const float* z = (const float*)d_in[7];
  const int* seq_len = (const int*)d_in[8];
  float* out = (float*)d_out;
  float* a_buf = (float*)d_ws;  // B_*S_ floats = 4 MB

  scores_kernel<<<B_ * (S_ / 64), 256, 0, stream>>>(
      seq_items, seq_pos, target_item, Wp, We, Wc, bias, z, seq_len, a_buf);
  softmax_kernel<<<B_, 256, 0, stream>>>(a_buf, seq_len, out);
  wsum_kernel<<<B_ * (S_ / 256), 256, 0, stream>>>(seq_items, a_buf, seq_len, out);
}